// Round 1
// baseline (850.670 us; speedup 1.0000x reference)
//
#include <hip/hip_runtime.h>
#include <hip/hip_bf16.h>

typedef __hip_bfloat16 bf16;

#define NB 8
#define NC 256
#define NQK 32
#define NH 128
#define NW 128
#define NHW 16384

static __device__ __forceinline__ float b2f(bf16 v){ return __bfloat162float(v); }
static __device__ __forceinline__ bf16  f2b(float v){ return __float2bfloat16(v); }

// ---------------- prep: wvT[c][co] bf16 (transposed Wv), wqkT[c][64] fp32 ----------------
__global__ __launch_bounds__(256) void k_prep(const float* __restrict__ Wq,
                                              const float* __restrict__ Wk,
                                              const float* __restrict__ Wv,
                                              bf16* __restrict__ wvT,
                                              float* __restrict__ wqkT){
    int idx = blockIdx.x*256 + threadIdx.x;
    if (idx < 65536){
        int c = idx >> 8, co = idx & 255;
        wvT[c*256 + co] = f2b(Wv[co*256 + c]);
    } else {
        int i2 = idx - 65536;            // 0..16383
        int c = i2 >> 6, o = i2 & 63;
        wqkT[c*64 + o] = (o < 32) ? Wq[o*256 + c] : Wk[(o-32)*256 + c];
    }
}

// ---------------- qk conv: q,k = Wqk * x  (bf16 out, channel-major) ----------------
__global__ __launch_bounds__(256) void k_qk(const float* __restrict__ x,
                                            const float* __restrict__ wqkT,
                                            const float* __restrict__ bq,
                                            const float* __restrict__ bk,
                                            bf16* __restrict__ q,
                                            bf16* __restrict__ kk){
    __shared__ float wl[16384];   // [c][64] -> float4-able, broadcast reads
    __shared__ float bias[64];
    int t = threadIdx.x;
    for (int idx = t; idx < 16384; idx += 256) wl[idx] = wqkT[idx];
    if (t < 32) bias[t] = bq[t];
    else if (t < 64) bias[t] = bk[t-32];
    __syncthreads();
    int b = blockIdx.y;
    int p = blockIdx.x*256 + t;
    const float* xp = x + (size_t)b*NC*NHW + p;
    float acc[64];
    #pragma unroll
    for (int o=0;o<64;o++) acc[o]=0.f;
    for (int c=0;c<NC;c++){
        float xv = xp[(size_t)c*NHW];
        const float4* wp = (const float4*)&wl[c*64];
        #pragma unroll
        for (int m=0;m<16;m++){
            float4 w4 = wp[m];
            acc[m*4+0] += w4.x*xv;
            acc[m*4+1] += w4.y*xv;
            acc[m*4+2] += w4.z*xv;
            acc[m*4+3] += w4.w*xv;
        }
    }
    size_t qb = (size_t)b*NQK*NHW + p;
    #pragma unroll
    for (int o=0;o<32;o++) q [qb + (size_t)o*NHW] = f2b(acc[o]    + bias[o]);
    #pragma unroll
    for (int o=0;o<32;o++) kk[qb + (size_t)o*NHW] = f2b(acc[32+o] + bias[32+o]);
}

// ---------------- tiled transpose: x (fp32) and q,k (bf16) -> column-major bf16 ----------------
__global__ __launch_bounds__(256) void k_tr(const float* __restrict__ x,
                                            const bf16* __restrict__ q,
                                            const bf16* __restrict__ kk,
                                            bf16* __restrict__ xcm,
                                            bf16* __restrict__ qcm,
                                            bf16* __restrict__ kcm){
    __shared__ float tile[32][33];
    int img = blockIdx.y;                 // 0..2047 x, 2048..2303 q, 2304..2559 k
    int tw = blockIdx.x & 3, th = blockIdx.x >> 2;
    int tx = threadIdx.x, ty = threadIdx.y;   // 32 x 8
    int h0 = th*32, w0 = tw*32;
    if (img < 2048){
        const float* src = x + (size_t)img*NHW;
        #pragma unroll
        for (int r=0;r<4;r++)
            tile[ty + r*8][tx] = src[(size_t)(h0+ty+r*8)*NW + w0 + tx];
    } else if (img < 2304){
        const bf16* src = q + (size_t)(img-2048)*NHW;
        #pragma unroll
        for (int r=0;r<4;r++)
            tile[ty + r*8][tx] = b2f(src[(size_t)(h0+ty+r*8)*NW + w0 + tx]);
    } else {
        const bf16* src = kk + (size_t)(img-2304)*NHW;
        #pragma unroll
        for (int r=0;r<4;r++)
            tile[ty + r*8][tx] = b2f(src[(size_t)(h0+ty+r*8)*NW + w0 + tx]);
    }
    __syncthreads();
    bf16* dst = (img < 2048) ? (xcm + (size_t)img*NHW)
              : (img < 2304) ? (qcm + (size_t)(img-2048)*NHW)
                             : (kcm + (size_t)(img-2304)*NHW);
    #pragma unroll
    for (int r=0;r<4;r++)
        dst[(size_t)(w0+ty+r*8)*NH + h0 + tx] = f2b(tile[tx][ty+r*8]);
}

// ---------------- column attention: PH=exp(eH) (diag masked), aggH = PH * x_col ----------------
// block = (w, b), 512 threads. Writes UNNORMALIZED aggH (bf16) and lH row-sums (fp32).
__global__ __launch_bounds__(512) void k_colagg(const bf16* __restrict__ qcm,
                                                const bf16* __restrict__ kcm,
                                                const bf16* __restrict__ xcm,
                                                bf16* __restrict__ agg,
                                                float* __restrict__ lH){
    __shared__ float ph[128*132];   // [j][i], pad 132 keeps float4 align + bank spread
    __shared__ float reg2[16512];   // union: {qc[32][128], kc[32][128]} then xcf[128][129]
    __shared__ float ps[512];
    int t = threadIdx.x;
    int w = blockIdx.x, b = blockIdx.y;
    for (int idx = t; idx < 4096; idx += 512){
        int c = idx >> 7, i = idx & 127;
        reg2[idx]        = b2f(qcm[((size_t)(b*NQK + c)*NW + w)*NH + i]);
        reg2[4096 + idx] = b2f(kcm[((size_t)(b*NQK + c)*NW + w)*NH + i]);
    }
    __syncthreads();
    {   // phase 1: eH -> exp -> ph, row partial sums
        int i = t & 127, jg = t >> 7;   // 4 j-groups of 32
        float qreg[32];
        #pragma unroll
        for (int c=0;c<32;c++) qreg[c] = reg2[c*128 + i];
        float psum = 0.f;
        for (int jj=0;jj<32;jj++){
            int j = jg*32 + jj;
            float dot = 0.f;
            #pragma unroll
            for (int c=0;c<32;c++) dot += qreg[c]*reg2[4096 + c*128 + j];
            float pv = (j == i) ? 0.f : __expf(dot);   // diag mask == exp(-inf)=0
            ph[j*132 + i] = pv;
            psum += pv;
        }
        ps[jg*128 + i] = psum;
    }
    __syncthreads();
    if (t < 128)
        lH[(size_t)(b*NH + t)*NW + w] = ps[t]+ps[128+t]+ps[256+t]+ps[384+t];
    int cgrp = t & 31, igrp = t >> 5;
    int i0 = igrp*8;
    for (int half=0; half<2; half++){
        for (int idx = t; idx < 16384; idx += 512){
            int c = idx >> 7, j = idx & 127;
            reg2[c*129 + j] = b2f(xcm[((size_t)(b*NC + half*128 + c)*NW + w)*NH + j]);
        }
        __syncthreads();
        float acc[8][4];
        #pragma unroll
        for (int ii=0;ii<8;ii++)
            #pragma unroll
            for (int cc=0;cc<4;cc++) acc[ii][cc]=0.f;
        for (int j=0;j<128;j++){
            const float4* php = (const float4*)&ph[j*132 + i0];
            float4 pa = php[0], pb = php[1];
            float pv[8] = {pa.x,pa.y,pa.z,pa.w,pb.x,pb.y,pb.z,pb.w};
            float xv[4];
            #pragma unroll
            for (int cc=0;cc<4;cc++) xv[cc] = reg2[(cgrp + 32*cc)*129 + j];
            #pragma unroll
            for (int ii=0;ii<8;ii++)
                #pragma unroll
                for (int cc=0;cc<4;cc++) acc[ii][cc] += pv[ii]*xv[cc];
        }
        #pragma unroll
        for (int ii=0;ii<8;ii++){
            size_t base = ((size_t)(b*NH + (i0+ii))*NW + w)*NC + half*128 + cgrp;
            #pragma unroll
            for (int cc=0;cc<4;cc++)
                agg[base + cc*32] = f2b(acc[ii][cc]);
        }
        __syncthreads();
    }
}

// ---------------- row attention: PW=exp(eW), agg = (aggH + PW*x_row) / (lH+lW) ----------------
__global__ __launch_bounds__(512) void k_rowagg(const bf16* __restrict__ q,
                                                const bf16* __restrict__ kk,
                                                const float* __restrict__ x,
                                                bf16* __restrict__ agg,
                                                const float* __restrict__ lH){
    __shared__ float ph[128*132];
    __shared__ float reg2[16512];
    __shared__ float ps[512];
    __shared__ float linv[128];
    int t = threadIdx.x;
    int h = blockIdx.x, b = blockIdx.y;
    for (int idx = t; idx < 4096; idx += 512){
        int c = idx >> 7, i = idx & 127;
        reg2[idx]        = b2f(q [((size_t)(b*NQK + c)*NH + h)*NW + i]);
        reg2[4096 + idx] = b2f(kk[((size_t)(b*NQK + c)*NH + h)*NW + i]);
    }
    __syncthreads();
    {
        int i = t & 127, jg = t >> 7;
        float qreg[32];
        #pragma unroll
        for (int c=0;c<32;c++) qreg[c] = reg2[c*128 + i];
        float psum = 0.f;
        for (int jj=0;jj<32;jj++){
            int j = jg*32 + jj;
            float dot = 0.f;
            #pragma unroll
            for (int c=0;c<32;c++) dot += qreg[c]*reg2[4096 + c*128 + j];
            float pv = __expf(dot);          // no diag mask on row branch
            ph[j*132 + i] = pv;
            psum += pv;
        }
        ps[jg*128 + i] = psum;
    }
    __syncthreads();
    if (t < 128){
        float lw = ps[t]+ps[128+t]+ps[256+t]+ps[384+t];
        float lh = lH[(size_t)(b*NH + h)*NW + t];
        linv[t] = 1.f/(lh + lw);
    }
    int cgrp = t & 31, igrp = t >> 5;
    int i0 = igrp*8;
    for (int half=0; half<2; half++){
        for (int idx = t; idx < 16384; idx += 512){
            int c = idx >> 7, j = idx & 127;
            reg2[c*129 + j] = x[(size_t)(b*NC + half*128 + c)*NHW + h*NW + j];
        }
        __syncthreads();   // also guarantees linv[] visible
        float acc[8][4];
        #pragma unroll
        for (int ii=0;ii<8;ii++)
            #pragma unroll
            for (int cc=0;cc<4;cc++) acc[ii][cc]=0.f;
        for (int j=0;j<128;j++){
            const float4* php = (const float4*)&ph[j*132 + i0];
            float4 pa = php[0], pb = php[1];
            float pv[8] = {pa.x,pa.y,pa.z,pa.w,pb.x,pb.y,pb.z,pb.w};
            float xv[4];
            #pragma unroll
            for (int cc=0;cc<4;cc++) xv[cc] = reg2[(cgrp + 32*cc)*129 + j];
            #pragma unroll
            for (int ii=0;ii<8;ii++)
                #pragma unroll
                for (int cc=0;cc<4;cc++) acc[ii][cc] += pv[ii]*xv[cc];
        }
        #pragma unroll
        for (int ii=0;ii<8;ii++){
            float li = linv[i0+ii];
            size_t base = ((size_t)(b*NH + h)*NW + (i0+ii))*NC + half*128 + cgrp;
            #pragma unroll
            for (int cc=0;cc<4;cc++){
                size_t a2 = base + cc*32;
                float s = (b2f(agg[a2]) + acc[ii][cc]) * li;
                agg[a2] = f2b(s);
            }
        }
        __syncthreads();
    }
}

// ---------------- final: out = gamma*(Wv*agg + bv) + x ----------------
__global__ __launch_bounds__(512) void k_final(const bf16* __restrict__ agg,
                                               const bf16* __restrict__ wvT,
                                               const float* __restrict__ bv,
                                               const float* __restrict__ gamma,
                                               const float* __restrict__ x,
                                               float* __restrict__ out){
    __shared__ float wl[16384];     // [cc_local][co] fp32, broadcast float4 reads
    __shared__ float ag[128*65];    // [p][cc_local], pad 65 -> bank-free
    int t = threadIdx.x;
    int b = blockIdx.y;
    int p0 = blockIdx.x*128;
    int pi = t & 127, cg = t >> 7;   // cg 0..3 -> 64 co each
    float acc[64];
    #pragma unroll
    for (int o=0;o<64;o++) acc[o]=0.f;
    for (int ck=0; ck<4; ck++){
        for (int idx = t; idx < 16384; idx += 512){
            int co = idx & 255, ccl = idx >> 8;
            wl[ccl*256 + co] = b2f(wvT[(size_t)(ck*64 + ccl)*256 + co]);
        }
        for (int idx = t; idx < 8192; idx += 512){
            int ccl = idx & 63, p = idx >> 6;
            ag[p*65 + ccl] = b2f(agg[(size_t)(b*NHW + p0 + p)*NC + ck*64 + ccl]);
        }
        __syncthreads();
        for (int cc=0; cc<64; cc++){
            float av = ag[pi*65 + cc];
            const float4* wp = (const float4*)&wl[cc*256 + cg*64];
            #pragma unroll
            for (int m=0;m<16;m++){
                float4 w4 = wp[m];
                acc[m*4+0] += w4.x*av;
                acc[m*4+1] += w4.y*av;
                acc[m*4+2] += w4.z*av;
                acc[m*4+3] += w4.w*av;
            }
        }
        __syncthreads();
    }
    float g = gamma[0];
    #pragma unroll
    for (int o=0;o<64;o++){
        int co = cg*64 + o;
        size_t oidx = ((size_t)(b*NC + co))*NHW + p0 + pi;
        out[oidx] = g*(acc[o] + bv[co]) + x[oidx];
    }
}

extern "C" void kernel_launch(void* const* d_in, const int* in_sizes, int n_in,
                              void* d_out, int out_size, void* d_ws, size_t ws_size,
                              hipStream_t stream){
    (void)in_sizes; (void)n_in; (void)out_size; (void)ws_size;
    const float* x     = (const float*)d_in[0];
    const float* Wq    = (const float*)d_in[1];
    const float* bq    = (const float*)d_in[2];
    const float* Wk    = (const float*)d_in[3];
    const float* bk    = (const float*)d_in[4];
    const float* Wv    = (const float*)d_in[5];
    const float* bv    = (const float*)d_in[6];
    const float* gamma = (const float*)d_in[7];
    float* out = (float*)d_out;
    char* ws = (char*)d_ws;

    bf16*  q    = (bf16*) (ws + 0);          //  8,388,608  [b][32][h][w]
    bf16*  kk   = (bf16*) (ws + 8388608);    //  8,388,608
    bf16*  qcm  = (bf16*) (ws + 16777216);   //  8,388,608  [b][32][w][h]
    bf16*  kcm  = (bf16*) (ws + 25165824);   //  8,388,608
    bf16*  xcm  = (bf16*) (ws + 33554432);   // 67,108,864  [b][c][w][h]
    float* lH   = (float*)(ws + 100663296);  //    524,288  [b][i][w]
    bf16*  wvT  = (bf16*) (ws + 101187584);  //    131,072  [c][co]
    float* wqkT = (float*)(ws + 101318656);  //    262,144  [c][64]
    bf16*  agg  = (bf16*) (ws + 101580800);  // 67,108,864  [b][i][w][c] position-major
    // total ws: 168,689,664 bytes

    k_prep  <<<dim3(320),      dim3(256),    0, stream>>>(Wq, Wk, Wv, wvT, wqkT);
    k_qk    <<<dim3(64, 8),    dim3(256),    0, stream>>>(x, wqkT, bq, bk, q, kk);
    k_tr    <<<dim3(16, 2560), dim3(32, 8),  0, stream>>>(x, q, kk, xcm, qcm, kcm);
    k_colagg<<<dim3(128, 8),   dim3(512),    0, stream>>>(qcm, kcm, xcm, agg, lH);
    k_rowagg<<<dim3(128, 8),   dim3(512),    0, stream>>>(q, kk, x, agg, lH);
    k_final <<<dim3(128, 8),   dim3(512),    0, stream>>>(agg, wvT, bv, gamma, x, out);
}

// Round 2
// 659.580 us; speedup vs baseline: 1.2897x; 1.2897x over previous
//
#include <hip/hip_runtime.h>
#include <hip/hip_bf16.h>

typedef __hip_bfloat16 bf16;
typedef __attribute__((ext_vector_type(8))) short bf16x8;
typedef __attribute__((ext_vector_type(4))) float f32x4;

#define NB 8
#define NC 256
#define NQK 32
#define NH 128
#define NW 128
#define NHW 16384

static __device__ __forceinline__ float b2f(bf16 v){ return __bfloat162float(v); }
static __device__ __forceinline__ bf16  f2b(float v){ return __float2bfloat16(v); }

// ---------------- prep: wvb[co][c] bf16 (Wv cast, row-major), wqkT[c][64] fp32 ----------------
__global__ __launch_bounds__(256) void k_prep(const float* __restrict__ Wq,
                                              const float* __restrict__ Wk,
                                              const float* __restrict__ Wv,
                                              bf16* __restrict__ wvb,
                                              float* __restrict__ wqkT){
    int idx = blockIdx.x*256 + threadIdx.x;
    if (idx < 65536){
        wvb[idx] = f2b(Wv[idx]);          // straight cast, row-major [co][c]
    } else {
        int i2 = idx - 65536;            // 0..16383
        int c = i2 >> 6, o = i2 & 63;
        wqkT[c*64 + o] = (o < 32) ? Wq[o*256 + c] : Wk[(o-32)*256 + c];
    }
}

// ---------------- qk conv: q,k = Wqk * x  (bf16 out, channel-major) ----------------
__global__ __launch_bounds__(256) void k_qk(const float* __restrict__ x,
                                            const float* __restrict__ wqkT,
                                            const float* __restrict__ bq,
                                            const float* __restrict__ bk,
                                            bf16* __restrict__ q,
                                            bf16* __restrict__ kk){
    __shared__ float wl[16384];   // [c][64] -> float4-able, broadcast reads
    __shared__ float bias[64];
    int t = threadIdx.x;
    for (int idx = t; idx < 16384; idx += 256) wl[idx] = wqkT[idx];
    if (t < 32) bias[t] = bq[t];
    else if (t < 64) bias[t] = bk[t-32];
    __syncthreads();
    int b = blockIdx.y;
    int p = blockIdx.x*256 + t;
    const float* xp = x + (size_t)b*NC*NHW + p;
    float acc[64];
    #pragma unroll
    for (int o=0;o<64;o++) acc[o]=0.f;
    for (int c=0;c<NC;c++){
        float xv = xp[(size_t)c*NHW];
        const float4* wp = (const float4*)&wl[c*64];
        #pragma unroll
        for (int m=0;m<16;m++){
            float4 w4 = wp[m];
            acc[m*4+0] += w4.x*xv;
            acc[m*4+1] += w4.y*xv;
            acc[m*4+2] += w4.z*xv;
            acc[m*4+3] += w4.w*xv;
        }
    }
    size_t qb = (size_t)b*NQK*NHW + p;
    #pragma unroll
    for (int o=0;o<32;o++) q [qb + (size_t)o*NHW] = f2b(acc[o]    + bias[o]);
    #pragma unroll
    for (int o=0;o<32;o++) kk[qb + (size_t)o*NHW] = f2b(acc[32+o] + bias[32+o]);
}

// ---------------- tiled transpose: x (fp32) and q,k (bf16) -> column-major bf16 ----------------
__global__ __launch_bounds__(256) void k_tr(const float* __restrict__ x,
                                            const bf16* __restrict__ q,
                                            const bf16* __restrict__ kk,
                                            bf16* __restrict__ xcm,
                                            bf16* __restrict__ qcm,
                                            bf16* __restrict__ kcm){
    __shared__ float tile[32][33];
    int img = blockIdx.y;                 // 0..2047 x, 2048..2303 q, 2304..2559 k
    int tw = blockIdx.x & 3, th = blockIdx.x >> 2;
    int tx = threadIdx.x, ty = threadIdx.y;   // 32 x 8
    int h0 = th*32, w0 = tw*32;
    if (img < 2048){
        const float* src = x + (size_t)img*NHW;
        #pragma unroll
        for (int r=0;r<4;r++)
            tile[ty + r*8][tx] = src[(size_t)(h0+ty+r*8)*NW + w0 + tx];
    } else if (img < 2304){
        const bf16* src = q + (size_t)(img-2048)*NHW;
        #pragma unroll
        for (int r=0;r<4;r++)
            tile[ty + r*8][tx] = b2f(src[(size_t)(h0+ty+r*8)*NW + w0 + tx]);
    } else {
        const bf16* src = kk + (size_t)(img-2304)*NHW;
        #pragma unroll
        for (int r=0;r<4;r++)
            tile[ty + r*8][tx] = b2f(src[(size_t)(h0+ty+r*8)*NW + w0 + tx]);
    }
    __syncthreads();
    bf16* dst = (img < 2048) ? (xcm + (size_t)img*NHW)
              : (img < 2304) ? (qcm + (size_t)(img-2048)*NHW)
                             : (kcm + (size_t)(img-2304)*NHW);
    #pragma unroll
    for (int r=0;r<4;r++)
        dst[(size_t)(w0+ty+r*8)*NH + h0 + tx] = f2b(tile[tx][ty+r*8]);
}

// ---------------- column attention: PH=exp(eH) (diag masked), aggH = PH * x_col ----------------
// block = (w, b), 512 threads. Writes UNNORMALIZED aggH (bf16) and lH row-sums (fp32).
__global__ __launch_bounds__(512) void k_colagg(const bf16* __restrict__ qcm,
                                                const bf16* __restrict__ kcm,
                                                const bf16* __restrict__ xcm,
                                                bf16* __restrict__ agg,
                                                float* __restrict__ lH){
    __shared__ float ph[128*132];   // [j][i], pad 132 keeps float4 align + bank spread
    __shared__ float reg2[16512];   // union: {qc[32][128], kc[32][128]} then xcf[128][129]
    __shared__ float ps[512];
    int t = threadIdx.x;
    int w = blockIdx.x, b = blockIdx.y;
    for (int idx = t; idx < 4096; idx += 512){
        int c = idx >> 7, i = idx & 127;
        reg2[idx]        = b2f(qcm[((size_t)(b*NQK + c)*NW + w)*NH + i]);
        reg2[4096 + idx] = b2f(kcm[((size_t)(b*NQK + c)*NW + w)*NH + i]);
    }
    __syncthreads();
    {   // phase 1: eH -> exp -> ph, row partial sums
        int i = t & 127, jg = t >> 7;   // 4 j-groups of 32
        float qreg[32];
        #pragma unroll
        for (int c=0;c<32;c++) qreg[c] = reg2[c*128 + i];
        float psum = 0.f;
        for (int jj=0;jj<32;jj++){
            int j = jg*32 + jj;
            float dot = 0.f;
            #pragma unroll
            for (int c=0;c<32;c++) dot += qreg[c]*reg2[4096 + c*128 + j];
            float pv = (j == i) ? 0.f : __expf(dot);   // diag mask == exp(-inf)=0
            ph[j*132 + i] = pv;
            psum += pv;
        }
        ps[jg*128 + i] = psum;
    }
    __syncthreads();
    if (t < 128)
        lH[(size_t)(b*NH + t)*NW + w] = ps[t]+ps[128+t]+ps[256+t]+ps[384+t];
    int cgrp = t & 31, igrp = t >> 5;
    int i0 = igrp*8;
    for (int half=0; half<2; half++){
        for (int idx = t; idx < 16384; idx += 512){
            int c = idx >> 7, j = idx & 127;
            reg2[c*129 + j] = b2f(xcm[((size_t)(b*NC + half*128 + c)*NW + w)*NH + j]);
        }
        __syncthreads();
        float acc[8][4];
        #pragma unroll
        for (int ii=0;ii<8;ii++)
            #pragma unroll
            for (int cc=0;cc<4;cc++) acc[ii][cc]=0.f;
        for (int j=0;j<128;j++){
            const float4* php = (const float4*)&ph[j*132 + i0];
            float4 pa = php[0], pb = php[1];
            float pv[8] = {pa.x,pa.y,pa.z,pa.w,pb.x,pb.y,pb.z,pb.w};
            float xv[4];
            #pragma unroll
            for (int cc=0;cc<4;cc++) xv[cc] = reg2[(cgrp + 32*cc)*129 + j];
            #pragma unroll
            for (int ii=0;ii<8;ii++)
                #pragma unroll
                for (int cc=0;cc<4;cc++) acc[ii][cc] += pv[ii]*xv[cc];
        }
        #pragma unroll
        for (int ii=0;ii<8;ii++){
            size_t base = ((size_t)(b*NH + (i0+ii))*NW + w)*NC + half*128 + cgrp;
            #pragma unroll
            for (int cc=0;cc<4;cc++)
                agg[base + cc*32] = f2b(acc[ii][cc]);
        }
        __syncthreads();
    }
}

// ---------------- row attention: PW=exp(eW), agg = (aggH + PW*x_row) / (lH+lW) ----------------
__global__ __launch_bounds__(512) void k_rowagg(const bf16* __restrict__ q,
                                                const bf16* __restrict__ kk,
                                                const float* __restrict__ x,
                                                bf16* __restrict__ agg,
                                                const float* __restrict__ lH){
    __shared__ float ph[128*132];
    __shared__ float reg2[16512];
    __shared__ float ps[512];
    __shared__ float linv[128];
    int t = threadIdx.x;
    int h = blockIdx.x, b = blockIdx.y;
    for (int idx = t; idx < 4096; idx += 512){
        int c = idx >> 7, i = idx & 127;
        reg2[idx]        = b2f(q [((size_t)(b*NQK + c)*NH + h)*NW + i]);
        reg2[4096 + idx] = b2f(kk[((size_t)(b*NQK + c)*NH + h)*NW + i]);
    }
    __syncthreads();
    {
        int i = t & 127, jg = t >> 7;
        float qreg[32];
        #pragma unroll
        for (int c=0;c<32;c++) qreg[c] = reg2[c*128 + i];
        float psum = 0.f;
        for (int jj=0;jj<32;jj++){
            int j = jg*32 + jj;
            float dot = 0.f;
            #pragma unroll
            for (int c=0;c<32;c++) dot += qreg[c]*reg2[4096 + c*128 + j];
            float pv = __expf(dot);          // no diag mask on row branch
            ph[j*132 + i] = pv;
            psum += pv;
        }
        ps[jg*128 + i] = psum;
    }
    __syncthreads();
    if (t < 128){
        float lw = ps[t]+ps[128+t]+ps[256+t]+ps[384+t];
        float lh = lH[(size_t)(b*NH + h)*NW + t];
        linv[t] = 1.f/(lh + lw);
    }
    int cgrp = t & 31, igrp = t >> 5;
    int i0 = igrp*8;
    for (int half=0; half<2; half++){
        for (int idx = t; idx < 16384; idx += 512){
            int c = idx >> 7, j = idx & 127;
            reg2[c*129 + j] = x[(size_t)(b*NC + half*128 + c)*NHW + h*NW + j];
        }
        __syncthreads();   // also guarantees linv[] visible
        float acc[8][4];
        #pragma unroll
        for (int ii=0;ii<8;ii++)
            #pragma unroll
            for (int cc=0;cc<4;cc++) acc[ii][cc]=0.f;
        for (int j=0;j<128;j++){
            const float4* php = (const float4*)&ph[j*132 + i0];
            float4 pa = php[0], pb = php[1];
            float pv[8] = {pa.x,pa.y,pa.z,pa.w,pb.x,pb.y,pb.z,pb.w};
            float xv[4];
            #pragma unroll
            for (int cc=0;cc<4;cc++) xv[cc] = reg2[(cgrp + 32*cc)*129 + j];
            #pragma unroll
            for (int ii=0;ii<8;ii++)
                #pragma unroll
                for (int cc=0;cc<4;cc++) acc[ii][cc] += pv[ii]*xv[cc];
        }
        #pragma unroll
        for (int ii=0;ii<8;ii++){
            float li = linv[i0+ii];
            size_t base = ((size_t)(b*NH + h)*NW + (i0+ii))*NC + half*128 + cgrp;
            #pragma unroll
            for (int cc=0;cc<4;cc++){
                size_t a2 = base + cc*32;
                float s = (b2f(agg[a2]) + acc[ii][cc]) * li;
                agg[a2] = f2b(s);
            }
        }
        __syncthreads();
    }
}

// ---------------- final (MFMA): out = gamma*(Wv*agg + bv) + x ----------------
// 256 threads = 4 waves; block tile = 256co x 64p; wave w -> co [w*64, w*64+64).
// A = wvb[co][c] bf16 row-major, B = agg[b][p][c] (c contiguous): both fragments
// are contiguous 16B/lane loads, no LDS. K=256 in 8 steps of 32.
// Maps (16x16x32): A: lane=16*(k/8)+m, elem=k%8; B: lane=16*(k/8)+n, elem=k%8;
// D: row=(lane>>4)*4+reg, col=lane&15.
__global__ __launch_bounds__(256) void k_final(const bf16* __restrict__ agg,
                                               const bf16* __restrict__ wvb,
                                               const float* __restrict__ bv,
                                               const float* __restrict__ gamma,
                                               const float* __restrict__ x,
                                               float* __restrict__ out){
    int t = threadIdx.x;
    int wave = t >> 6, l = t & 63;
    int lr = l & 15, lg = l >> 4;
    int b = blockIdx.y;
    int p0 = blockIdx.x * 64;
    int co0 = wave * 64;
    f32x4 acc[4][4] = {};
    const bf16* aggp = agg + ((size_t)b*NHW + p0 + lr)*NC + lg*8;
    const bf16* wp   = wvb + (size_t)(co0 + lr)*NC + lg*8;
    for (int kb = 0; kb < 8; kb++){
        bf16x8 af[4], bfr[4];
        #pragma unroll
        for (int m=0;m<4;m++)
            af[m] = *(const bf16x8*)(wp + (size_t)(m*16)*NC + kb*32);
        #pragma unroll
        for (int n=0;n<4;n++)
            bfr[n] = *(const bf16x8*)(aggp + (size_t)(n*16)*NC + kb*32);
        #pragma unroll
        for (int m=0;m<4;m++)
            #pragma unroll
            for (int n=0;n<4;n++)
                acc[m][n] = __builtin_amdgcn_mfma_f32_16x16x32_bf16(af[m], bfr[n], acc[m][n], 0,0,0);
    }
    float g = gamma[0];
    #pragma unroll
    for (int m=0;m<4;m++){
        #pragma unroll
        for (int r=0;r<4;r++){
            int co = co0 + m*16 + lg*4 + r;
            float bvv = bv[co];
            size_t rowbase = ((size_t)(b*NC + co))*NHW + p0;
            #pragma unroll
            for (int n=0;n<4;n++){
                size_t oi = rowbase + n*16 + lr;
                out[oi] = g*(acc[m][n][r] + bvv) + x[oi];
            }
        }
    }
}

extern "C" void kernel_launch(void* const* d_in, const int* in_sizes, int n_in,
                              void* d_out, int out_size, void* d_ws, size_t ws_size,
                              hipStream_t stream){
    (void)in_sizes; (void)n_in; (void)out_size; (void)ws_size;
    const float* x     = (const float*)d_in[0];
    const float* Wq    = (const float*)d_in[1];
    const float* bq    = (const float*)d_in[2];
    const float* Wk    = (const float*)d_in[3];
    const float* bk    = (const float*)d_in[4];
    const float* Wv    = (const float*)d_in[5];
    const float* bv    = (const float*)d_in[6];
    const float* gamma = (const float*)d_in[7];
    float* out = (float*)d_out;
    char* ws = (char*)d_ws;

    bf16*  q    = (bf16*) (ws + 0);          //  8,388,608  [b][32][h][w]
    bf16*  kk   = (bf16*) (ws + 8388608);    //  8,388,608
    bf16*  qcm  = (bf16*) (ws + 16777216);   //  8,388,608  [b][32][w][h]
    bf16*  kcm  = (bf16*) (ws + 25165824);   //  8,388,608
    bf16*  xcm  = (bf16*) (ws + 33554432);   // 67,108,864  [b][c][w][h]
    float* lH   = (float*)(ws + 100663296);  //    524,288  [b][i][w]
    bf16*  wvb  = (bf16*) (ws + 101187584);  //    131,072  [co][c] row-major bf16
    float* wqkT = (float*)(ws + 101318656);  //    262,144  [c][64]
    bf16*  agg  = (bf16*) (ws + 101580800);  // 67,108,864  [b][p][c] position-major
    // total ws: 168,689,664 bytes

    k_prep  <<<dim3(320),      dim3(256),    0, stream>>>(Wq, Wk, Wv, wvb, wqkT);
    k_qk    <<<dim3(64, 8),    dim3(256),    0, stream>>>(x, wqkT, bq, bk, q, kk);
    k_tr    <<<dim3(16, 2560), dim3(32, 8),  0, stream>>>(x, q, kk, xcm, qcm, kcm);
    k_colagg<<<dim3(128, 8),   dim3(512),    0, stream>>>(qcm, kcm, xcm, agg, lH);
    k_rowagg<<<dim3(128, 8),   dim3(512),    0, stream>>>(q, kk, x, agg, lH);
    k_final <<<dim3(256, 8),   dim3(256),    0, stream>>>(agg, wvb, bv, gamma, x, out);
}

// Round 3
// 353.098 us; speedup vs baseline: 2.4092x; 1.8680x over previous
//
#include <hip/hip_runtime.h>
#include <hip/hip_bf16.h>

typedef __hip_bfloat16 bf16;
typedef __attribute__((ext_vector_type(8))) short bf16x8;
typedef __attribute__((ext_vector_type(4))) float f32x4;

#define NB 8
#define NC 256
#define NQK 32
#define NH 128
#define NW 128
#define NHW 16384
#define PSTR 136   // LDS row stride (elems) for P and X tiles: 272B = 17*16B (b128-aligned, 4-dword bank skew)

static __device__ __forceinline__ float b2f(bf16 v){ return __bfloat162float(v); }
static __device__ __forceinline__ bf16  f2b(float v){ return __float2bfloat16(v); }

// ---------------- prep: wvb[co][c] bf16 (Wv cast, row-major), wqkT[c][64] fp32 ----------------
__global__ __launch_bounds__(256) void k_prep(const float* __restrict__ Wq,
                                              const float* __restrict__ Wk,
                                              const float* __restrict__ Wv,
                                              bf16* __restrict__ wvb,
                                              float* __restrict__ wqkT){
    int idx = blockIdx.x*256 + threadIdx.x;
    if (idx < 65536){
        wvb[idx] = f2b(Wv[idx]);          // straight cast, row-major [co][c]
    } else {
        int i2 = idx - 65536;            // 0..16383
        int c = i2 >> 6, o = i2 & 63;
        wqkT[c*64 + o] = (o < 32) ? Wq[o*256 + c] : Wk[(o-32)*256 + c];
    }
}

// ---------------- qk conv: qrw/krw[b][p][32] = Wqk * x  (position-major bf16) ----------------
__global__ __launch_bounds__(256) void k_qk(const float* __restrict__ x,
                                            const float* __restrict__ wqkT,
                                            const float* __restrict__ bq,
                                            const float* __restrict__ bk,
                                            bf16* __restrict__ qrw,
                                            bf16* __restrict__ krw){
    __shared__ float wl[16384];   // [c][64]
    __shared__ float bias[64];
    int t = threadIdx.x;
    for (int idx = t; idx < 16384; idx += 256) wl[idx] = wqkT[idx];
    if (t < 32) bias[t] = bq[t];
    else if (t < 64) bias[t] = bk[t-32];
    __syncthreads();
    int b = blockIdx.y;
    int p = blockIdx.x*256 + t;
    const float* xp = x + (size_t)b*NC*NHW + p;
    float acc[64];
    #pragma unroll
    for (int o=0;o<64;o++) acc[o]=0.f;
    for (int c=0;c<NC;c++){
        float xv = xp[(size_t)c*NHW];
        const float4* wp = (const float4*)&wl[c*64];
        #pragma unroll
        for (int m=0;m<16;m++){
            float4 w4 = wp[m];
            acc[m*4+0] += w4.x*xv;
            acc[m*4+1] += w4.y*xv;
            acc[m*4+2] += w4.z*xv;
            acc[m*4+3] += w4.w*xv;
        }
    }
    union { bf16 h[32]; bf16x8 v[4]; } oq, ok;
    #pragma unroll
    for (int o=0;o<32;o++) oq.h[o] = f2b(acc[o]    + bias[o]);
    #pragma unroll
    for (int o=0;o<32;o++) ok.h[o] = f2b(acc[32+o] + bias[32+o]);
    bf16* qp = qrw + ((size_t)b*NHW + p)*NQK;
    bf16* kp = krw + ((size_t)b*NHW + p)*NQK;
    #pragma unroll
    for (int m=0;m<4;m++){ *(bf16x8*)(qp + m*8) = oq.v[m]; *(bf16x8*)(kp + m*8) = ok.v[m]; }
}

// ---------------- tiled transpose: x fp32 [c][h][w] -> xcm bf16 [c][w][h] ----------------
__global__ __launch_bounds__(256) void k_tr(const float* __restrict__ x,
                                            bf16* __restrict__ xcm){
    __shared__ float tile[32][33];
    int img = blockIdx.y;                 // 0..2047 (b*c)
    int tw = blockIdx.x & 3, th = blockIdx.x >> 2;
    int tx = threadIdx.x, ty = threadIdx.y;   // 32 x 8
    int h0 = th*32, w0 = tw*32;
    const float* src = x + (size_t)img*NHW;
    #pragma unroll
    for (int r=0;r<4;r++)
        tile[ty + r*8][tx] = src[(size_t)(h0+ty+r*8)*NW + w0 + tx];
    __syncthreads();
    bf16* dst = xcm + (size_t)img*NHW;
    #pragma unroll
    for (int r=0;r<4;r++)
        dst[(size_t)(w0+ty+r*8)*NH + h0 + tx] = f2b(tile[tx][ty+r*8]);
}

// ---------------- column attention (MFMA) ----------------
// block = (w, b), 512 thr = 8 waves; wave wv owns i-tile mi = wv.
// Phase1: e[i][j] = sum_c q[c,i,w] k[c,j,w] via one 16x16x32 MFMA per (mi,nj);
//         P = exp(e) (diag->0) -> LDS bf16 [i][PSTR]; row sums -> lH (unnormalized).
// Phase2: agg[i][c] = sum_j P[i][j] x[c,j(h),w], computed as D[c][i] = mfma(A=X rows, B=P rows);
//         lane's 4 acc values contiguous in c -> 8B packed stores.
__global__ __launch_bounds__(512) void k_colagg(const bf16* __restrict__ qrw,
                                                const bf16* __restrict__ krw,
                                                const bf16* __restrict__ xcm,
                                                bf16* __restrict__ agg,
                                                float* __restrict__ lH){
    __shared__ __align__(16) bf16 Pl[128*PSTR];
    __shared__ __align__(16) bf16 Xl[128*PSTR];
    __shared__ float lsum[128];
    int t = threadIdx.x;
    int wv = t >> 6, l = t & 63, lr = l & 15, lg = l >> 4;
    int w = blockIdx.x, b = blockIdx.y;
    int mi = wv;
    // ---- phase 1: QK^T + exp + P store + row sums ----
    bf16x8 af = *(const bf16x8*)(qrw + ((size_t)(b*NH + mi*16 + lr)*NW + w)*NQK + lg*8);
    float sreg[4] = {0.f,0.f,0.f,0.f};
    f32x4 zero = {0.f,0.f,0.f,0.f};
    for (int nj=0; nj<8; nj++){
        bf16x8 bfr = *(const bf16x8*)(krw + ((size_t)(b*NH + nj*16 + lr)*NW + w)*NQK + lg*8);
        f32x4 e = __builtin_amdgcn_mfma_f32_16x16x32_bf16(af, bfr, zero, 0,0,0);
        #pragma unroll
        for (int r=0;r<4;r++){
            int i = mi*16 + lg*4 + r;
            int j = nj*16 + lr;
            float pv = (i == j) ? 0.f : __expf(e[r]);
            Pl[i*PSTR + j] = f2b(pv);
            sreg[r] += pv;
        }
    }
    #pragma unroll
    for (int m=1;m<16;m<<=1)
        #pragma unroll
        for (int r=0;r<4;r++) sreg[r] += __shfl_xor(sreg[r], m);
    if (lr == 0){
        #pragma unroll
        for (int r=0;r<4;r++) lsum[mi*16 + lg*4 + r] = sreg[r];
    }
    __syncthreads();
    if (t < 128) lH[((size_t)(b*NH + t))*NW + w] = lsum[t];
    // ---- phase 2: P * X (two 128-channel halves) ----
    for (int half=0; half<2; half++){
        #pragma unroll
        for (int cc=0; cc<4; cc++){
            int gi = cc*512 + t;
            int c = gi >> 4, seg = gi & 15;
            bf16x8 v = *(const bf16x8*)(xcm + ((size_t)(b*NC + half*128 + c)*NW + w)*NH + seg*8);
            *(bf16x8*)(Xl + c*PSTR + seg*8) = v;
        }
        __syncthreads();
        bf16x8 xa[4];
        #pragma unroll
        for (int kb=0;kb<4;kb++)
            xa[kb] = *(const bf16x8*)(Xl + (wv*16 + lr)*PSTR + kb*32 + lg*8);
        for (int nj=0;nj<8;nj++){
            f32x4 acc = zero;
            #pragma unroll
            for (int kb=0;kb<4;kb++){
                bf16x8 pb = *(const bf16x8*)(Pl + (nj*16 + lr)*PSTR + kb*32 + lg*8);
                acc = __builtin_amdgcn_mfma_f32_16x16x32_bf16(xa[kb], pb, acc, 0,0,0);
            }
            int i  = nj*16 + lr;
            int cb = half*128 + wv*16 + lg*4;
            union { ushort4 u; bf16 h[4]; } pk;
            #pragma unroll
            for (int r=0;r<4;r++) pk.h[r] = f2b(acc[r]);
            *(ushort4*)(agg + ((size_t)(b*NHW + i*NW + w))*NC + cb) = pk.u;
        }
        __syncthreads();
    }
}

// ---------------- row attention (MFMA): agg = (aggH + PW*x_row) / (lH+lW) ----------------
__global__ __launch_bounds__(512) void k_rowagg(const bf16* __restrict__ qrw,
                                                const bf16* __restrict__ krw,
                                                const float* __restrict__ x,
                                                bf16* __restrict__ agg,
                                                const float* __restrict__ lH){
    __shared__ __align__(16) bf16 Pl[128*PSTR];
    __shared__ __align__(16) bf16 Xl[128*PSTR];
    __shared__ float lsum[128];
    __shared__ float linv[128];
    int t = threadIdx.x;
    int wv = t >> 6, l = t & 63, lr = l & 15, lg = l >> 4;
    int h = blockIdx.x, b = blockIdx.y;
    int mi = wv;
    // ---- phase 1 ----
    bf16x8 af = *(const bf16x8*)(qrw + ((size_t)(b*NH + h)*NW + mi*16 + lr)*NQK + lg*8);
    float sreg[4] = {0.f,0.f,0.f,0.f};
    f32x4 zero = {0.f,0.f,0.f,0.f};
    for (int nj=0; nj<8; nj++){
        bf16x8 bfr = *(const bf16x8*)(krw + ((size_t)(b*NH + h)*NW + nj*16 + lr)*NQK + lg*8);
        f32x4 e = __builtin_amdgcn_mfma_f32_16x16x32_bf16(af, bfr, zero, 0,0,0);
        #pragma unroll
        for (int r=0;r<4;r++){
            int i = mi*16 + lg*4 + r;
            int j = nj*16 + lr;
            float pv = __expf(e[r]);            // no diag mask on row branch
            Pl[i*PSTR + j] = f2b(pv);
            sreg[r] += pv;
        }
    }
    #pragma unroll
    for (int m=1;m<16;m<<=1)
        #pragma unroll
        for (int r=0;r<4;r++) sreg[r] += __shfl_xor(sreg[r], m);
    if (lr == 0){
        #pragma unroll
        for (int r=0;r<4;r++) lsum[mi*16 + lg*4 + r] = sreg[r];
    }
    __syncthreads();
    if (t < 128){
        float lh = lH[((size_t)(b*NH + h))*NW + t];
        linv[t] = 1.f/(lh + lsum[t]);
    }
    // ---- phase 2 ----
    for (int half=0; half<2; half++){
        #pragma unroll
        for (int cc=0; cc<4; cc++){
            int gi = cc*512 + t;
            int c = gi >> 4, seg = gi & 15;
            const float* xp = x + (size_t)(b*NC + half*128 + c)*NHW + h*NW + seg*8;
            float4 a0 = *(const float4*)(xp);
            float4 a1 = *(const float4*)(xp + 4);
            union { bf16x8 v; bf16 hh[8]; } u;
            u.hh[0]=f2b(a0.x); u.hh[1]=f2b(a0.y); u.hh[2]=f2b(a0.z); u.hh[3]=f2b(a0.w);
            u.hh[4]=f2b(a1.x); u.hh[5]=f2b(a1.y); u.hh[6]=f2b(a1.z); u.hh[7]=f2b(a1.w);
            *(bf16x8*)(Xl + c*PSTR + seg*8) = u.v;
        }
        __syncthreads();   // also makes linv visible
        bf16x8 xa[4];
        #pragma unroll
        for (int kb=0;kb<4;kb++)
            xa[kb] = *(const bf16x8*)(Xl + (wv*16 + lr)*PSTR + kb*32 + lg*8);
        for (int nj=0;nj<8;nj++){
            f32x4 acc = zero;
            #pragma unroll
            for (int kb=0;kb<4;kb++){
                bf16x8 pb = *(const bf16x8*)(Pl + (nj*16 + lr)*PSTR + kb*32 + lg*8);
                acc = __builtin_amdgcn_mfma_f32_16x16x32_bf16(xa[kb], pb, acc, 0,0,0);
            }
            int i  = nj*16 + lr;       // w coordinate
            int cb = half*128 + wv*16 + lg*4;
            float li = linv[i];
            size_t ai = ((size_t)(b*NHW + h*NW + i))*NC + cb;
            union { ushort4 u; bf16 hh[4]; } old, neu;
            old.u = *(const ushort4*)(agg + ai);
            #pragma unroll
            for (int r=0;r<4;r++) neu.hh[r] = f2b((b2f(old.hh[r]) + acc[r]) * li);
            *(ushort4*)(agg + ai) = neu.u;
        }
        __syncthreads();
    }
}

// ---------------- final (MFMA): out = gamma*(Wv*agg + bv) + x ----------------
__global__ __launch_bounds__(256) void k_final(const bf16* __restrict__ agg,
                                               const bf16* __restrict__ wvb,
                                               const float* __restrict__ bv,
                                               const float* __restrict__ gamma,
                                               const float* __restrict__ x,
                                               float* __restrict__ out){
    int t = threadIdx.x;
    int wave = t >> 6, l = t & 63;
    int lr = l & 15, lg = l >> 4;
    int b = blockIdx.y;
    int p0 = blockIdx.x * 64;
    int co0 = wave * 64;
    f32x4 acc[4][4] = {};
    const bf16* aggp = agg + ((size_t)b*NHW + p0 + lr)*NC + lg*8;
    const bf16* wp   = wvb + (size_t)(co0 + lr)*NC + lg*8;
    for (int kb = 0; kb < 8; kb++){
        bf16x8 af[4], bfr[4];
        #pragma unroll
        for (int m=0;m<4;m++)
            af[m] = *(const bf16x8*)(wp + (size_t)(m*16)*NC + kb*32);
        #pragma unroll
        for (int n=0;n<4;n++)
            bfr[n] = *(const bf16x8*)(aggp + (size_t)(n*16)*NC + kb*32);
        #pragma unroll
        for (int m=0;m<4;m++)
            #pragma unroll
            for (int n=0;n<4;n++)
                acc[m][n] = __builtin_amdgcn_mfma_f32_16x16x32_bf16(af[m], bfr[n], acc[m][n], 0,0,0);
    }
    float g = gamma[0];
    #pragma unroll
    for (int m=0;m<4;m++){
        #pragma unroll
        for (int r=0;r<4;r++){
            int co = co0 + m*16 + lg*4 + r;
            float bvv = bv[co];
            size_t rowbase = ((size_t)(b*NC + co))*NHW + p0;
            #pragma unroll
            for (int n=0;n<4;n++){
                size_t oi = rowbase + n*16 + lr;
                out[oi] = g*(acc[m][n][r] + bvv) + x[oi];
            }
        }
    }
}

extern "C" void kernel_launch(void* const* d_in, const int* in_sizes, int n_in,
                              void* d_out, int out_size, void* d_ws, size_t ws_size,
                              hipStream_t stream){
    (void)in_sizes; (void)n_in; (void)out_size; (void)ws_size;
    const float* x     = (const float*)d_in[0];
    const float* Wq    = (const float*)d_in[1];
    const float* bq    = (const float*)d_in[2];
    const float* Wk    = (const float*)d_in[3];
    const float* bk    = (const float*)d_in[4];
    const float* Wv    = (const float*)d_in[5];
    const float* bv    = (const float*)d_in[6];
    const float* gamma = (const float*)d_in[7];
    float* out = (float*)d_out;
    char* ws = (char*)d_ws;

    bf16*  qrw  = (bf16*) (ws + 0);          //  8,388,608  [b][p][32]
    bf16*  krw  = (bf16*) (ws + 8388608);    //  8,388,608  [b][p][32]
    bf16*  xcm  = (bf16*) (ws + 16777216);   // 67,108,864  [b][c][w][h]
    float* lH   = (float*)(ws + 83886080);   //    524,288  [b][i][w]
    bf16*  wvb  = (bf16*) (ws + 84410368);   //    131,072  [co][c]
    float* wqkT = (float*)(ws + 84541440);   //    262,144  [c][64]
    bf16*  agg  = (bf16*) (ws + 84803584);   // 67,108,864  [b][p][c]
    // total ws: 151,912,448 bytes

    k_prep  <<<dim3(320),      dim3(256),   0, stream>>>(Wq, Wk, Wv, wvb, wqkT);
    k_qk    <<<dim3(64, 8),    dim3(256),   0, stream>>>(x, wqkT, bq, bk, qrw, krw);
    k_tr    <<<dim3(16, 2048), dim3(32, 8), 0, stream>>>(x, xcm);
    k_colagg<<<dim3(128, 8),   dim3(512),   0, stream>>>(qrw, krw, xcm, agg, lH);
    k_rowagg<<<dim3(128, 8),   dim3(512),   0, stream>>>(qrw, krw, x, agg, lH);
    k_final <<<dim3(256, 8),   dim3(256),   0, stream>>>(agg, wvb, bv, gamma, x, out);
}

// Round 4
// 244.106 us; speedup vs baseline: 3.4848x; 1.4465x over previous
//
#include <hip/hip_runtime.h>
#include <hip/hip_bf16.h>

typedef __hip_bfloat16 bf16;
typedef __attribute__((ext_vector_type(8))) short bf16x8;
typedef __attribute__((ext_vector_type(4))) float f32x4;

#define NB 8
#define NC 256
#define NQK 32
#define NH 128
#define NW 128
#define NHW 16384
#define PSTR 136   // LDS row stride (elems): 272B = 17*16B, b128-aligned, 2-way banks (free)
#define QSTR 40    // k_qk Xl stride: 80B = 5*16B aligned

static __device__ __forceinline__ float b2f(bf16 v){ return __bfloat162float(v); }
static __device__ __forceinline__ bf16  f2b(float v){ return __float2bfloat16(v); }

// ---------------- prep: wvb[co][c] bf16, wqkb[o][c] bf16 (o<32: Wq row, o>=32: Wk row) --------
__global__ __launch_bounds__(256) void k_prep(const float* __restrict__ Wq,
                                              const float* __restrict__ Wk,
                                              const float* __restrict__ Wv,
                                              bf16* __restrict__ wvb,
                                              bf16* __restrict__ wqkb){
    int idx = blockIdx.x*256 + threadIdx.x;
    if (idx < 65536){
        wvb[idx] = f2b(Wv[idx]);                  // row-major [co][c]
    } else {
        int i2 = idx - 65536;                     // 0..16383 -> [64][256] flat
        wqkb[i2] = f2b(i2 < 8192 ? Wq[i2] : Wk[i2 - 8192]);
    }
}

// ---------------- qk conv (MFMA): q,k rows [b][p][32] = Wqk * x ----------------
// 512 thr = 8 waves; block p-tile 256. Per 32-c chunk: stage x^T into LDS via
// quad-shfl 4x4 transpose; A = wqkb rows (global, L2), B = Xl rows (p, c-contig).
// D: o = mt*16+lg*4+r (4 consec o -> ushort4 store), p = wv*32+nt*16+lr.
__global__ __launch_bounds__(512) void k_qk(const float* __restrict__ x,
                                            const bf16* __restrict__ wqkb,
                                            const float* __restrict__ bq,
                                            const float* __restrict__ bk,
                                            bf16* __restrict__ qrw,
                                            bf16* __restrict__ krw){
    __shared__ __align__(16) bf16 Xl[256*QSTR];
    int t = threadIdx.x;
    int wv = t >> 6, l = t & 63, lr = l & 15, lg = l >> 4;
    int b = blockIdx.y;
    int p0 = blockIdx.x * 256;
    int q4 = t & 3, pb = ((t >> 2) & 63) * 4, chi = t >> 8;   // chi 0/1
    f32x4 acc[4][2] = {};
    for (int kb = 0; kb < 8; kb++){
        if (kb) __syncthreads();
        #pragma unroll
        for (int it = 0; it < 4; it++){
            int cl = it*8 + chi*4;                // chunk-local c base (lane adds q4)
            const float* xp = x + ((size_t)(b*NC + kb*32 + cl + q4))*NHW + p0 + pb;
            float4 v = *(const float4*)xp;
            float e[4] = {v.x, v.y, v.z, v.w};
            // quad transpose: lane q4 ends with x[c=cl+0..3][p=pb+q4]
            float s1[4], s2[4];
            #pragma unroll
            for (int j=0;j<4;j++){
                float ex = __shfl_xor(e[j^1], 1);
                s1[j] = ((j&1)==(q4&1)) ? e[j] : ex;
            }
            #pragma unroll
            for (int j=0;j<4;j++){
                float ex = __shfl_xor(s1[j^2], 2);
                s2[j] = ((j&2)==(q4&2)) ? s1[j] : ex;
            }
            union { ushort4 u; bf16 h[4]; } pk;
            #pragma unroll
            for (int j=0;j<4;j++) pk.h[j] = f2b(s2[j]);
            *(ushort4*)(Xl + (pb + q4)*QSTR + cl) = pk.u;
        }
        __syncthreads();
        bf16x8 bf_[2];
        #pragma unroll
        for (int nt=0;nt<2;nt++)
            bf_[nt] = *(const bf16x8*)(Xl + (wv*32 + nt*16 + lr)*QSTR + lg*8);
        #pragma unroll
        for (int mt=0;mt<4;mt++){
            bf16x8 af = *(const bf16x8*)(wqkb + (size_t)(mt*16 + lr)*NC + kb*32 + lg*8);
            acc[mt][0] = __builtin_amdgcn_mfma_f32_16x16x32_bf16(af, bf_[0], acc[mt][0], 0,0,0);
            acc[mt][1] = __builtin_amdgcn_mfma_f32_16x16x32_bf16(af, bf_[1], acc[mt][1], 0,0,0);
        }
    }
    #pragma unroll
    for (int mt=0;mt<4;mt++){
        int o0 = mt*16 + lg*4;                        // 0..63
        float4 bb = (mt < 2) ? *(const float4*)(bq + o0)
                             : *(const float4*)(bk + o0 - 32);
        bf16* dst = (mt < 2) ? qrw : krw;
        int oo = (mt < 2) ? o0 : o0 - 32;             // 0..28
        #pragma unroll
        for (int nt=0;nt<2;nt++){
            int p = p0 + wv*32 + nt*16 + lr;
            union { ushort4 u; bf16 h[4]; } pk;
            pk.h[0] = f2b(acc[mt][nt][0] + bb.x);
            pk.h[1] = f2b(acc[mt][nt][1] + bb.y);
            pk.h[2] = f2b(acc[mt][nt][2] + bb.z);
            pk.h[3] = f2b(acc[mt][nt][3] + bb.w);
            *(ushort4*)(dst + ((size_t)b*NHW + p)*NQK + oo) = pk.u;
        }
    }
}

// ---------------- tiled transpose: x fp32 [c][h][w] -> xcm bf16 [c][w][h] ----------------
__global__ __launch_bounds__(256) void k_tr(const float* __restrict__ x,
                                            bf16* __restrict__ xcm){
    __shared__ float tile[32][33];
    int img = blockIdx.y;                 // 0..2047 (b*c)
    int tw = blockIdx.x & 3, th = blockIdx.x >> 2;
    int tx = threadIdx.x, ty = threadIdx.y;   // 32 x 8
    int h0 = th*32, w0 = tw*32;
    const float* src = x + (size_t)img*NHW;
    #pragma unroll
    for (int r=0;r<4;r++)
        tile[ty + r*8][tx] = src[(size_t)(h0+ty+r*8)*NW + w0 + tx];
    __syncthreads();
    bf16* dst = xcm + (size_t)img*NHW;
    #pragma unroll
    for (int r=0;r<4;r++)
        dst[(size_t)(w0+ty+r*8)*NH + h0 + tx] = f2b(tile[tx][ty+r*8]);
}

// ---------------- column attention (MFMA): unnormalized aggH + lH ----------------
__global__ __launch_bounds__(512) void k_colagg(const bf16* __restrict__ qrw,
                                                const bf16* __restrict__ krw,
                                                const bf16* __restrict__ xcm,
                                                bf16* __restrict__ agg,
                                                float* __restrict__ lH){
    __shared__ __align__(16) bf16 Pl[128*PSTR];
    __shared__ __align__(16) bf16 Xl[128*PSTR];
    __shared__ float lsum[128];
    int t = threadIdx.x;
    int wv = t >> 6, l = t & 63, lr = l & 15, lg = l >> 4;
    int w = blockIdx.x, b = blockIdx.y;
    int mi = wv;
    bf16x8 af = *(const bf16x8*)(qrw + ((size_t)(b*NH + mi*16 + lr)*NW + w)*NQK + lg*8);
    float sreg[4] = {0.f,0.f,0.f,0.f};
    f32x4 zero = {0.f,0.f,0.f,0.f};
    for (int nj=0; nj<8; nj++){
        bf16x8 bfr = *(const bf16x8*)(krw + ((size_t)(b*NH + nj*16 + lr)*NW + w)*NQK + lg*8);
        f32x4 e = __builtin_amdgcn_mfma_f32_16x16x32_bf16(af, bfr, zero, 0,0,0);
        #pragma unroll
        for (int r=0;r<4;r++){
            int i = mi*16 + lg*4 + r;
            int j = nj*16 + lr;
            float pv = (i == j) ? 0.f : __expf(e[r]);
            Pl[i*PSTR + j] = f2b(pv);
            sreg[r] += pv;
        }
    }
    #pragma unroll
    for (int m=1;m<16;m<<=1)
        #pragma unroll
        for (int r=0;r<4;r++) sreg[r] += __shfl_xor(sreg[r], m);
    if (lr == 0){
        #pragma unroll
        for (int r=0;r<4;r++) lsum[mi*16 + lg*4 + r] = sreg[r];
    }
    __syncthreads();
    if (t < 128) lH[((size_t)(b*NH + t))*NW + w] = lsum[t];
    for (int half=0; half<2; half++){
        #pragma unroll
        for (int cc=0; cc<4; cc++){
            int gi = cc*512 + t;
            int c = gi >> 4, seg = gi & 15;
            bf16x8 v = *(const bf16x8*)(xcm + ((size_t)(b*NC + half*128 + c)*NW + w)*NH + seg*8);
            *(bf16x8*)(Xl + c*PSTR + seg*8) = v;
        }
        __syncthreads();
        bf16x8 xa[4];
        #pragma unroll
        for (int kb=0;kb<4;kb++)
            xa[kb] = *(const bf16x8*)(Xl + (wv*16 + lr)*PSTR + kb*32 + lg*8);
        for (int nj=0;nj<8;nj++){
            f32x4 acc = zero;
            #pragma unroll
            for (int kb=0;kb<4;kb++){
                bf16x8 pb = *(const bf16x8*)(Pl + (nj*16 + lr)*PSTR + kb*32 + lg*8);
                acc = __builtin_amdgcn_mfma_f32_16x16x32_bf16(xa[kb], pb, acc, 0,0,0);
            }
            int i  = nj*16 + lr;
            int cb = half*128 + wv*16 + lg*4;
            union { ushort4 u; bf16 h[4]; } pk;
            #pragma unroll
            for (int r=0;r<4;r++) pk.h[r] = f2b(acc[r]);
            *(ushort4*)(agg + ((size_t)(b*NHW + i*NW + w))*NC + cb) = pk.u;
        }
        __syncthreads();
    }
}

// ---------------- fused row attention + final conv ----------------
// block (h, b), 512 thr = 8 waves.
// p1: PW=exp(QK^T) -> Pl; linv = 1/(lH+lW).
// per half: aggW via mfma(A=x rows direct-global, B=Pl rows); combine with aggH,
//   normalize -> AggL[128p][c-local]; partial Wv GEMM (K=128) from AggL into Facc.
// epilogue: out = g*(Facc+bv) + x, float4 along p.
__global__ __launch_bounds__(512) void k_rowfin(const bf16* __restrict__ qrw,
                                                const bf16* __restrict__ krw,
                                                const float* __restrict__ x,
                                                const bf16* __restrict__ aggH,
                                                const float* __restrict__ lH,
                                                const bf16* __restrict__ wvb,
                                                const float* __restrict__ bv,
                                                const float* __restrict__ gamma,
                                                float* __restrict__ out){
    __shared__ __align__(16) bf16 Pl[128*PSTR];
    __shared__ __align__(16) bf16 AggL[128*PSTR];
    __shared__ float lsum[128];
    __shared__ float linv[128];
    int t = threadIdx.x;
    int wv = t >> 6, l = t & 63, lr = l & 15, lg = l >> 4;
    int h = blockIdx.x, b = blockIdx.y;
    f32x4 zero = {0.f,0.f,0.f,0.f};
    // ---- p1: QK^T ----
    bf16x8 af = *(const bf16x8*)(qrw + ((size_t)(b*NH + h)*NW + wv*16 + lr)*NQK + lg*8);
    float sreg[4] = {0.f,0.f,0.f,0.f};
    for (int nj=0; nj<8; nj++){
        bf16x8 bfr = *(const bf16x8*)(krw + ((size_t)(b*NH + h)*NW + nj*16 + lr)*NQK + lg*8);
        f32x4 e = __builtin_amdgcn_mfma_f32_16x16x32_bf16(af, bfr, zero, 0,0,0);
        #pragma unroll
        for (int r=0;r<4;r++){
            int i = wv*16 + lg*4 + r;
            int j = nj*16 + lr;
            float pv = __expf(e[r]);
            Pl[i*PSTR + j] = f2b(pv);
            sreg[r] += pv;
        }
    }
    #pragma unroll
    for (int m=1;m<16;m<<=1)
        #pragma unroll
        for (int r=0;r<4;r++) sreg[r] += __shfl_xor(sreg[r], m);
    if (lr == 0){
        #pragma unroll
        for (int r=0;r<4;r++) lsum[wv*16 + lg*4 + r] = sreg[r];
    }
    __syncthreads();
    if (t < 128) linv[t] = 1.f/(lH[((size_t)(b*NH + h))*NW + t] + lsum[t]);
    f32x4 Facc[8][2] = {};
    for (int half=0; half<2; half++){
        // a: A-frags for aggW straight from global x (w-contiguous rows)
        bf16x8 xa[4];
        const float* xrow = x + ((size_t)(b*NC + half*128 + wv*16 + lr))*NHW + h*NW;
        #pragma unroll
        for (int kb=0;kb<4;kb++){
            float4 u0 = *(const float4*)(xrow + kb*32 + lg*8);
            float4 u1 = *(const float4*)(xrow + kb*32 + lg*8 + 4);
            union { bf16x8 v; bf16 hh[8]; } u;
            u.hh[0]=f2b(u0.x); u.hh[1]=f2b(u0.y); u.hh[2]=f2b(u0.z); u.hh[3]=f2b(u0.w);
            u.hh[4]=f2b(u1.x); u.hh[5]=f2b(u1.y); u.hh[6]=f2b(u1.z); u.hh[7]=f2b(u1.w);
            xa[kb] = u.v;
        }
        __syncthreads();   // orders prev-half AggL reads before new writes; Pl/linv visible
        // b: aggW + combine + normalize -> AggL
        for (int nj=0;nj<8;nj++){
            f32x4 acc = zero;
            #pragma unroll
            for (int kb=0;kb<4;kb++){
                bf16x8 pb = *(const bf16x8*)(Pl + (nj*16 + lr)*PSTR + kb*32 + lg*8);
                acc = __builtin_amdgcn_mfma_f32_16x16x32_bf16(xa[kb], pb, acc, 0,0,0);
            }
            int i  = nj*16 + lr;
            int c4 = wv*16 + lg*4;                 // c-local within half
            float li = linv[i];
            const bf16* ah = aggH + ((size_t)(b*NHW + h*NW + i))*NC + half*128 + c4;
            union { ushort4 u; bf16 hh[4]; } old, nu;
            old.u = *(const ushort4*)ah;
            #pragma unroll
            for (int r=0;r<4;r++) nu.hh[r] = f2b((b2f(old.hh[r]) + acc[r]) * li);
            *(ushort4*)(AggL + i*PSTR + c4) = nu.u;
        }
        __syncthreads();
        // c: partial Wv GEMM over this half (K=128)
        for (int kb2=0; kb2<4; kb2++){
            bf16x8 bw[2];
            #pragma unroll
            for (int nt=0;nt<2;nt++)
                bw[nt] = *(const bf16x8*)(wvb + (size_t)(wv*32 + nt*16 + lr)*NC + half*128 + kb2*32 + lg*8);
            #pragma unroll
            for (int pt=0;pt<8;pt++){
                bf16x8 aa = *(const bf16x8*)(AggL + (pt*16 + lr)*PSTR + kb2*32 + lg*8);
                Facc[pt][0] = __builtin_amdgcn_mfma_f32_16x16x32_bf16(aa, bw[0], Facc[pt][0], 0,0,0);
                Facc[pt][1] = __builtin_amdgcn_mfma_f32_16x16x32_bf16(aa, bw[1], Facc[pt][1], 0,0,0);
            }
        }
    }
    // epilogue: float4 along p (w)
    float g = gamma[0];
    #pragma unroll
    for (int nt=0;nt<2;nt++){
        int co = wv*32 + nt*16 + lr;
        float bvv = bv[co];
        const float* xr = x   + ((size_t)(b*NC + co))*NHW + h*NW;
        float*       orow = out + ((size_t)(b*NC + co))*NHW + h*NW;
        #pragma unroll
        for (int pt=0;pt<8;pt++){
            int p4 = pt*16 + lg*4;
            float4 xv = *(const float4*)(xr + p4);
            float4 ov;
            ov.x = g*(Facc[pt][nt][0] + bvv) + xv.x;
            ov.y = g*(Facc[pt][nt][1] + bvv) + xv.y;
            ov.z = g*(Facc[pt][nt][2] + bvv) + xv.z;
            ov.w = g*(Facc[pt][nt][3] + bvv) + xv.w;
            *(float4*)(orow + p4) = ov;
        }
    }
}

extern "C" void kernel_launch(void* const* d_in, const int* in_sizes, int n_in,
                              void* d_out, int out_size, void* d_ws, size_t ws_size,
                              hipStream_t stream){
    (void)in_sizes; (void)n_in; (void)out_size; (void)ws_size;
    const float* x     = (const float*)d_in[0];
    const float* Wq    = (const float*)d_in[1];
    const float* bq    = (const float*)d_in[2];
    const float* Wk    = (const float*)d_in[3];
    const float* bk    = (const float*)d_in[4];
    const float* Wv    = (const float*)d_in[5];
    const float* bv    = (const float*)d_in[6];
    const float* gamma = (const float*)d_in[7];
    float* out = (float*)d_out;
    char* ws = (char*)d_ws;

    bf16*  qrw  = (bf16*) (ws + 0);          //  8,388,608  [b][p][32]
    bf16*  krw  = (bf16*) (ws + 8388608);    //  8,388,608  [b][p][32]
    bf16*  xcm  = (bf16*) (ws + 16777216);   // 67,108,864  [b][c][w][h]
    float* lH   = (float*)(ws + 83886080);   //    524,288  [b][i][w]
    bf16*  wvb  = (bf16*) (ws + 84410368);   //    131,072  [co][c]
    bf16*  wqkb = (bf16*) (ws + 84541440);   //     32,768  [64][256]
    bf16*  aggH = (bf16*) (ws + 84574208);   // 67,108,864  [b][p][c] unnormalized column agg
    // total ws: 151,683,072 bytes

    k_prep  <<<dim3(320),      dim3(256),   0, stream>>>(Wq, Wk, Wv, wvb, wqkb);
    k_qk    <<<dim3(64, 8),    dim3(512),   0, stream>>>(x, wqkb, bq, bk, qrw, krw);
    k_tr    <<<dim3(16, 2048), dim3(32, 8), 0, stream>>>(x, xcm);
    k_colagg<<<dim3(128, 8),   dim3(512),   0, stream>>>(qrw, krw, xcm, aggH, lH);
    k_rowfin<<<dim3(128, 8),   dim3(512),   0, stream>>>(qrw, krw, x, aggH, lH, wvb, bv, gamma, out);
}